// Round 3
// baseline (613.620 us; speedup 1.0000x reference)
//
#include <hip/hip_runtime.h>

// ---------------------------------------------------------------------------
// PairEdgeLearnGNN on MI355X.  B=64, N=1024, D=128, KT=13, NC=2, CF=2.
//   scores = x (w1 w2^T) x^T ; adj = softmax over axis=1 (columns)
//   h = (adj + I) x ; g = h gin_w^T + gin_b ; BN1 per-n over (b,d)
//   z[b,c,d] = sum_n bn1(g) lc_w[c,n] ; conv K=13 SAME ; BN2 ; relu ; linear ; softmax
// Outputs: probs (64x2) then adj (64x1024x1024), f32, concatenated.
// ---------------------------------------------------------------------------

typedef __attribute__((ext_vector_type(8))) short bf16x8;
typedef __attribute__((ext_vector_type(4))) float f32x4;

__device__ __forceinline__ float b2f(unsigned short s){
  union { unsigned u; float f; } v; v.u = ((unsigned)s) << 16; return v.f;
}
__device__ __forceinline__ unsigned short f2b(float f){
  union { float f; unsigned u; } v; v.f = f;
  unsigned r = v.u + 0x7fffu + ((v.u >> 16) & 1u);
  return (unsigned short)(r >> 16);
}

#define MFMA16(a, b, c) __builtin_amdgcn_mfma_f32_16x16x32_bf16((a), (b), (c), 0, 0, 0)

// ---------------------------------------------------------------------------
// prep (all vectorized):
//  [0,4096)      x -> xb bf16 cast, 16B stores
//  [4096,6144)   64x64 transpose tiles -> xbT, 16B stores
//  [6144,6152)   gin_w -> bf16
//  [6152,6216)   Mt[d][k] = sum_e w1[k,e] w2[d,e]
// ---------------------------------------------------------------------------
__global__ __launch_bounds__(256) void k_prep(
    const float* __restrict__ x, const float* __restrict__ w1, const float* __restrict__ w2,
    const float* __restrict__ gin_w,
    unsigned short* __restrict__ xb, unsigned short* __restrict__ xbT,
    unsigned short* __restrict__ mt, unsigned short* __restrict__ ginb)
{
  int blk = blockIdx.x, tid = threadIdx.x;
  if (blk < 4096) {
    size_t i = ((size_t)blk << 11) + (tid << 3);
    float4 a = *(const float4*)&x[i];
    float4 c = *(const float4*)&x[i + 4];
    bf16x8 r;
    r[0]=(short)f2b(a.x); r[1]=(short)f2b(a.y); r[2]=(short)f2b(a.z); r[3]=(short)f2b(a.w);
    r[4]=(short)f2b(c.x); r[5]=(short)f2b(c.y); r[6]=(short)f2b(c.z); r[7]=(short)f2b(c.w);
    *(bf16x8*)&xb[i] = r;
  } else if (blk < 6144) {
    __shared__ float tile[64][65];
    int t = blk - 4096;
    int b = t >> 5, tt = t & 31;
    int j0 = (tt >> 1) << 6, d0 = (tt & 1) << 6;
    int row = tid >> 2, cq = tid & 3;
#pragma unroll
    for (int q = 0; q < 4; q++) {
      float4 v = *(const float4*)&x[(((size_t)(b << 10) + j0 + row) << 7) + d0 + (cq << 4) + (q << 2)];
      int c = (cq << 4) + (q << 2);
      tile[row][c] = v.x; tile[row][c+1] = v.y; tile[row][c+2] = v.z; tile[row][c+3] = v.w;
    }
    __syncthreads();
    int d = tid >> 2, jq = tid & 3;
#pragma unroll
    for (int q = 0; q < 2; q++) {
      bf16x8 r;
#pragma unroll
      for (int e = 0; e < 8; e++)
        r[e] = (short)f2b(tile[(jq << 4) + (q << 3) + e][d]);
      *(bf16x8*)&xbT[(((size_t)(b << 7) + d0 + d) << 10) + j0 + (jq << 4) + (q << 3)] = r;
    }
  } else if (blk < 6152) {
    int i = ((blk - 6144) << 11) + (tid << 3);
    float4 a = *(const float4*)&gin_w[i];
    float4 c = *(const float4*)&gin_w[i + 4];
    bf16x8 r;
    r[0]=(short)f2b(a.x); r[1]=(short)f2b(a.y); r[2]=(short)f2b(a.z); r[3]=(short)f2b(a.w);
    r[4]=(short)f2b(c.x); r[5]=(short)f2b(c.y); r[6]=(short)f2b(c.z); r[7]=(short)f2b(c.w);
    *(bf16x8*)&ginb[i] = r;
  } else {
    int i = ((blk - 6152) << 8) + tid;
    int d = i >> 7, k = i & 127;
    float s = 0.f;
    for (int e = 0; e < 128; ++e) s += w1[(k << 7) + e] * w2[(d << 7) + e];
    mt[(d << 7) + k] = f2b(s);
  }
}

// ---------------------------------------------------------------------------
// NT GEMM, M x 128, K=128, 16 rows/wave, 64 rows/block, coalesced bf16 out
// via padded LDS bounce.
// ---------------------------------------------------------------------------
__global__ __launch_bounds__(256, 4) void k_gemm_nt128(
    const unsigned short* __restrict__ A, const unsigned short* __restrict__ Bt,
    const float* __restrict__ bias, unsigned short* __restrict__ Out)
{
  __shared__ unsigned short sm[64 * 132];
  int row0 = blockIdx.x << 6;
  int tid = threadIdx.x;
  int wave = tid >> 6, lane = tid & 63, lr = lane & 15, lg = lane >> 4;
  int rw = row0 + (wave << 4);
  bf16x8 af[4];
#pragma unroll
  for (int kk = 0; kk < 4; kk++)
    af[kk] = *(const bf16x8*)&A[((size_t)(rw + lr) << 7) + (kk << 5) + (lg << 3)];
  f32x4 acc[8] = {};
#pragma unroll
  for (int kk = 0; kk < 4; kk++) {
    bf16x8 bb[8];
#pragma unroll
    for (int cf = 0; cf < 8; cf++)
      bb[cf] = *(const bf16x8*)&Bt[(((cf << 4) + lr) << 7) + (kk << 5) + (lg << 3)];
#pragma unroll
    for (int cf = 0; cf < 8; cf++)
      acc[cf] = MFMA16(af[kk], bb[cf], acc[cf]);
  }
#pragma unroll
  for (int cf = 0; cf < 8; cf++) {
    int col = (cf << 4) + lr;
    float bv = bias ? bias[col] : 0.f;
    int srow = (wave << 4) + (lg << 2);
#pragma unroll
    for (int r = 0; r < 4; r++)
      sm[(srow + r) * 132 + col] = f2b(acc[cf][r] + bv);
  }
  __syncthreads();
#pragma unroll
  for (int p = 0; p < 4; p++) {
    int rowl = (p << 4) + (tid >> 4);
    int c0 = (tid & 15) << 3;
    bf16x8 v = *(const bf16x8*)&sm[rowl * 132 + c0];
    *(bf16x8*)&Out[((size_t)(row0 + rowl) << 7) + c0] = v;
  }
}

// ---------------------------------------------------------------------------
// colsum: per (b, it) 64 rows (16/wave), loop jt, barrier-free, per-wave
// deterministic partials psum[it*4+wave][b*1024+j]. XCD-swizzled.
// ---------------------------------------------------------------------------
__global__ __launch_bounds__(256, 4) void k_colsum(
    const unsigned short* __restrict__ qb, const unsigned short* __restrict__ xb,
    float* __restrict__ psum)
{
  int bid = blockIdx.x;
  int l = ((bid & 7) << 7) + (bid >> 3);
  int b = l >> 4, it = l & 15;
  int i0 = it << 6;
  int tid = threadIdx.x, wave = tid >> 6, lane = tid & 63, lr = lane & 15, lg = lane >> 4;
  const unsigned short* Ab = qb + ((size_t)b << 17);
  const unsigned short* Bb = xb + ((size_t)b << 17);
  bf16x8 af[4];
#pragma unroll
  for (int kk = 0; kk < 4; kk++)
    af[kk] = *(const bf16x8*)&Ab[((size_t)(i0 + (wave << 4) + lr) << 7) + (kk << 5) + (lg << 3)];

  for (int jt = 0; jt < 8; jt++) {
    int j0 = jt << 7;
    f32x4 s[8] = {};
#pragma unroll
    for (int kk = 0; kk < 4; kk++) {
      bf16x8 bb[8];
#pragma unroll
      for (int cf = 0; cf < 8; cf++)
        bb[cf] = *(const bf16x8*)&Bb[((size_t)(j0 + (cf << 4) + lr) << 7) + (kk << 5) + (lg << 3)];
#pragma unroll
      for (int cf = 0; cf < 8; cf++)
        s[cf] = MFMA16(af[kk], bb[cf], s[cf]);
    }
#pragma unroll
    for (int cf = 0; cf < 8; cf++) {
      float p = 0.f;
#pragma unroll
      for (int r = 0; r < 4; r++) p += __expf(s[cf][r]);
      p += __shfl_xor(p, 16);
      p += __shfl_xor(p, 32);
      if (lane < 16)
        psum[(size_t)((it << 2) + wave) * 65536 + (b << 10) + j0 + (cf << 4) + lane] = p;
    }
  }
}

__global__ void k_rcol(const float* __restrict__ psum, float* __restrict__ rcol)
{
  int i = (blockIdx.x << 8) + threadIdx.x;
  float s = 0.f;
#pragma unroll
  for (int p = 0; p < 64; p++) s += psum[(size_t)p * 65536 + i];
  rcol[i] = 1.f / s;
}

// ---------------------------------------------------------------------------
// fused adj + h = (adj+I)x.  64 rows/block (16/wave), grid 1024 (4 blocks/CU),
// barrier-free jt loop; per-wave swizzled LDS P-tile serves BOTH the PV
// transpose AND a coalesced (512B-run) nontemporal adj store readback.
// ---------------------------------------------------------------------------
__global__ __launch_bounds__(256, 4) void k_attn(
    const unsigned short* __restrict__ qb, const unsigned short* __restrict__ xb,
    const unsigned short* __restrict__ xbT, const float* __restrict__ rcol,
    float* __restrict__ adj, unsigned short* __restrict__ hb)
{
  int bid = blockIdx.x;
  int l = ((bid & 7) << 7) + (bid >> 3);      // XCD r gets b in [r*8, r*8+8)
  int b = l >> 4, it = l & 15;
  int i0 = it << 6;
  int tid = threadIdx.x, wave = tid >> 6, lane = tid & 63, lr = lane & 15, lg = lane >> 4;
  __shared__ unsigned short plds[4][16][128];   // per-wave private, chunk^row swizzle
  __shared__ float rc[1024];
  const unsigned short* Ab = qb + ((size_t)b << 17);
  const unsigned short* Xb = xb + ((size_t)b << 17);
  const unsigned short* Xt = xbT + ((size_t)b << 17);

  rc[tid] = rcol[(b << 10) + tid];
  rc[tid + 256] = rcol[(b << 10) + tid + 256];
  rc[tid + 512] = rcol[(b << 10) + tid + 512];
  rc[tid + 768] = rcol[(b << 10) + tid + 768];

  int rwave = i0 + (wave << 4);
  bf16x8 af[4];
#pragma unroll
  for (int kk = 0; kk < 4; kk++)
    af[kk] = *(const bf16x8*)&Ab[((size_t)(rwave + lr) << 7) + (kk << 5) + (lg << 3)];

  __syncthreads();   // rc ready; no further block barriers

  f32x4 h[8] = {};
  for (int jt = 0; jt < 8; jt++) {
    int j0 = jt << 7;
    f32x4 s[8] = {};
#pragma unroll
    for (int kk = 0; kk < 4; kk++) {
      bf16x8 bb[8];
#pragma unroll
      for (int cf = 0; cf < 8; cf++)
        bb[cf] = *(const bf16x8*)&Xb[((size_t)(j0 + (cf << 4) + lr) << 7) + (kk << 5) + (lg << 3)];
#pragma unroll
      for (int cf = 0; cf < 8; cf++)
        s[cf] = MFMA16(af[kk], bb[cf], s[cf]);
    }

    // exp * rcol -> swizzled per-wave LDS (bf16)
#pragma unroll
    for (int cf = 0; cf < 8; cf++) {
      int colj = (cf << 4) + lr;
      float rv = rc[j0 + colj];
#pragma unroll
      for (int r = 0; r < 4; r++) {
        int lrow = (lg << 2) + r;            // 0..15
        float p = __expf(s[cf][r]) * rv;
        int sw = (colj >> 3) ^ lrow;         // 4-bit chunk swizzle
        plds[wave][lrow][(sw << 3) | (colj & 7)] = f2b(p);
      }
    }
    // no barrier: plds slice is wave-private

    // PV: h += P @ x
#pragma unroll
    for (int kk = 0; kk < 4; kk++) {
      bf16x8 pa, vb[8];
      pa = *(const bf16x8*)&plds[wave][lr][(((kk << 2) + lg) ^ lr) << 3];
#pragma unroll
      for (int cf = 0; cf < 8; cf++)
        vb[cf] = *(const bf16x8*)&Xt[(((size_t)((cf << 4) + lr)) << 10) + j0 + (kk << 5) + (lg << 3)];
#pragma unroll
      for (int cf = 0; cf < 8; cf++)
        h[cf] = MFMA16(pa, vb[cf], h[cf]);
    }

    // coalesced adj store: 16 lanes x 32B = 512B runs per row, nontemporal
#pragma unroll
    for (int p = 0; p < 4; p++) {
      int lrow = (p << 2) + (lane >> 4);
      int c0 = lane & 15;
      bf16x8 v = *(const bf16x8*)&plds[wave][lrow][(c0 ^ lrow) << 3];
      f32x4 lo, hi;
      lo[0]=b2f((unsigned short)v[0]); lo[1]=b2f((unsigned short)v[1]);
      lo[2]=b2f((unsigned short)v[2]); lo[3]=b2f((unsigned short)v[3]);
      hi[0]=b2f((unsigned short)v[4]); hi[1]=b2f((unsigned short)v[5]);
      hi[2]=b2f((unsigned short)v[6]); hi[3]=b2f((unsigned short)v[7]);
      float* dst = &adj[((size_t)((b << 10) + rwave + lrow) << 10) + j0 + (c0 << 3)];
      __builtin_nontemporal_store(lo, (f32x4*)dst);
      __builtin_nontemporal_store(hi, (f32x4*)(dst + 4));
    }
  }

  // epilogue: bounce h through plds, add x, coalesced bf16 store
#pragma unroll
  for (int cf = 0; cf < 8; cf++) {
    int colj = (cf << 4) + lr;
#pragma unroll
    for (int r = 0; r < 4; r++) {
      int lrow = (lg << 2) + r;
      int sw = (colj >> 3) ^ lrow;
      plds[wave][lrow][(sw << 3) | (colj & 7)] = f2b(h[cf][r]);
    }
  }
#pragma unroll
  for (int p = 0; p < 4; p++) {
    int lrow = (p << 2) + (lane >> 4);
    int c0 = lane & 15;
    bf16x8 v = *(const bf16x8*)&plds[wave][lrow][(c0 ^ lrow) << 3];
    bf16x8 xv = *(const bf16x8*)&Xb[((size_t)(rwave + lrow) << 7) + (c0 << 3)];
    bf16x8 o;
#pragma unroll
    for (int e = 0; e < 8; e++)
      o[e] = (short)f2b(b2f((unsigned short)v[e]) + b2f((unsigned short)xv[e]));
    *(bf16x8*)&hb[((size_t)((b << 10) + rwave + lrow) << 7) + (c0 << 3)] = o;
  }
}

// ---------------------------------------------------------------------------
// BN1 stats per n over (b,d) -> folded lc weights
// ---------------------------------------------------------------------------
__global__ __launch_bounds__(256) void k_bnstats(
    const unsigned short* __restrict__ gb, const float* __restrict__ lc_w,
    const float* __restrict__ lc_b, const float* __restrict__ bn1_g,
    const float* __restrict__ bn1_b, float* __restrict__ wprime, float* __restrict__ bterm)
{
  int n = blockIdx.x, tid = threadIdx.x;
  float s = 0.f, s2 = 0.f;
  for (int i = tid; i < 8192; i += 256) {
    int b = i >> 7, d = i & 127;
    float v = b2f(gb[((size_t)((b << 10) + n) << 7) + d]);
    s += v; s2 += v * v;
  }
  __shared__ float rs[256], rs2[256];
  rs[tid] = s; rs2[tid] = s2;
  __syncthreads();
  for (int o = 128; o > 0; o >>= 1) {
    if (tid < o) { rs[tid] += rs[tid + o]; rs2[tid] += rs2[tid + o]; }
    __syncthreads();
  }
  if (tid == 0) {
    float m = rs[0] * (1.f / 8192.f);
    float var = rs2[0] * (1.f / 8192.f) - m * m;
    float r = rsqrtf(var + 1e-5f);
    float rg = r * bn1_g[n];
    float t = bn1_b[n] - m * rg;
#pragma unroll
    for (int c = 0; c < 2; c++) {
      float w = lc_w[(c << 10) + n];
      wprime[(c << 10) + n] = w * rg;
      float bt = w * t;
      if (n == 0) bt += lc_b[c];
      bterm[(c << 10) + n] = bt;
    }
  }
}

__global__ __launch_bounds__(128) void k_zred(
    const unsigned short* __restrict__ gb, const float* __restrict__ wprime,
    float* __restrict__ zp)
{
  int blk = blockIdx.x;
  int b = blk >> 3, nc = blk & 7, n0 = nc << 7, d = threadIdx.x;
  float a0 = 0.f, a1 = 0.f;
  for (int n = n0; n < n0 + 128; ++n) {
    float w0 = wprime[n], w1v = wprime[1024 + n];
    float g = b2f(gb[((size_t)((b << 10) + n) << 7) + d]);
    a0 += g * w0; a1 += g * w1v;
  }
  zp[(size_t)nc * 16384 + ((b << 1) << 7) + d] = a0;
  zp[(size_t)nc * 16384 + (((b << 1) | 1) << 7) + d] = a1;
}

__global__ __launch_bounds__(1024) void k_final(
    const float* __restrict__ zp, const float* __restrict__ bterm,
    const float* __restrict__ conv_w, const float* __restrict__ conv_b,
    const float* __restrict__ bn2_g, const float* __restrict__ bn2_b,
    const float* __restrict__ out_w, const float* __restrict__ out_b,
    float* __restrict__ probs)
{
  __shared__ float smem[16384];
  __shared__ float bp[2], ms[2];
  __shared__ float cw[26];
  int tid = threadIdx.x;
  if (tid < 26) cw[tid] = conv_w[tid];

  for (int c = 0; c < 2; c++) {
    smem[tid] = bterm[(c << 10) + tid];
    __syncthreads();
    for (int o = 512; o > 0; o >>= 1) {
      if (tid < o) smem[tid] += smem[tid + o];
      __syncthreads();
    }
    if (tid == 0) bp[c] = smem[0];
    __syncthreads();
  }

  for (int i = tid; i < 16384; i += 1024) {
    float s = 0.f;
#pragma unroll
    for (int p = 0; p < 8; p++) s += zp[(size_t)p * 16384 + i];
    smem[i] = s + bp[(i >> 7) & 1];
  }
  __syncthreads();

  float o[8];
  float s = 0.f, s2 = 0.f;
#pragma unroll
  for (int k = 0; k < 8; k++) {
    int i = tid + (k << 10);
    int b = i >> 7, d = i & 127;
    float acc = conv_b[0];
#pragma unroll
    for (int c = 0; c < 2; c++) {
      const float* zrow = &smem[((b << 1) | c) << 7];
#pragma unroll
      for (int t = 0; t < 13; t++) {
        int dd = d + t - 6;
        if (dd >= 0 && dd < 128) acc += zrow[dd] * cw[c * 13 + t];
      }
    }
    o[k] = acc; s += acc; s2 += acc * acc;
  }
  __syncthreads();
  smem[tid] = s; smem[1024 + tid] = s2;
  __syncthreads();
  for (int off = 512; off > 0; off >>= 1) {
    if (tid < off) { smem[tid] += smem[tid + off]; smem[1024 + tid] += smem[1024 + tid + off]; }
    __syncthreads();
  }
  if (tid == 0) {
    float m = smem[0] * (1.f / 8192.f);
    float var = smem[1024] * (1.f / 8192.f) - m * m;
    ms[0] = m; ms[1] = rsqrtf(var + 1e-5f);
  }
  __syncthreads();
  float m = ms[0], r = ms[1], g2 = bn2_g[0], b2v = bn2_b[0];
#pragma unroll
  for (int k = 0; k < 8; k++) {
    int i = tid + (k << 10);
    smem[i & 8191] = fmaxf(0.f, (o[k] - m) * r * g2 + b2v);
  }
  __syncthreads();

  int b = tid >> 4, q = tid & 15;
  float l0 = 0.f, l1 = 0.f;
#pragma unroll
  for (int k = 0; k < 8; k++) {
    int d = q + (k << 4);
    float uv = smem[(b << 7) + d];
    l0 += uv * out_w[d];
    l1 += uv * out_w[128 + d];
  }
#pragma unroll
  for (int off = 8; off > 0; off >>= 1) { l0 += __shfl_xor(l0, off); l1 += __shfl_xor(l1, off); }
  if (q == 0) {
    l0 += out_b[0]; l1 += out_b[1];
    float mm = fmaxf(l0, l1);
    float e0 = __expf(l0 - mm), e1 = __expf(l1 - mm);
    float inv = 1.f / (e0 + e1);
    probs[(b << 1)] = e0 * inv;
    probs[(b << 1) | 1] = e1 * inv;
  }
}

// ---------------------------------------------------------------------------
extern "C" void kernel_launch(void* const* d_in, const int* in_sizes, int n_in,
                              void* d_out, int out_size, void* d_ws, size_t ws_size,
                              hipStream_t stream)
{
  const float* x      = (const float*)d_in[0];
  const float* w1     = (const float*)d_in[1];
  const float* w2     = (const float*)d_in[2];
  const float* gin_w  = (const float*)d_in[3];
  const float* gin_b  = (const float*)d_in[4];
  const float* bn1_g  = (const float*)d_in[5];
  const float* bn1_b  = (const float*)d_in[6];
  const float* lc_w   = (const float*)d_in[7];
  const float* lc_b   = (const float*)d_in[8];
  const float* conv_w = (const float*)d_in[9];
  const float* conv_b = (const float*)d_in[10];
  const float* bn2_g  = (const float*)d_in[11];
  const float* bn2_b  = (const float*)d_in[12];
  const float* out_w  = (const float*)d_in[13];
  const float* out_b  = (const float*)d_in[14];

  char* ws = (char*)d_ws;
  unsigned short* xb   = (unsigned short*)(ws);                       // 16 MiB
  unsigned short* xbT  = (unsigned short*)(ws + ((size_t)16 << 20));  // 16 MiB
  unsigned short* qb   = (unsigned short*)(ws + ((size_t)32 << 20));  // 16 MiB
  unsigned short* hb   = (unsigned short*)(ws + ((size_t)48 << 20));  // 16 MiB
  float* psum = (float*)hb;            // alias: psum dead before hb written
  unsigned short* mt   = (unsigned short*)(ws + ((size_t)64 << 20));            // 32 KiB
  unsigned short* ginb = (unsigned short*)(ws + ((size_t)64 << 20) + (32u << 10));
  float* rcolp  = (float*)(ws + ((size_t)64 << 20) + (64u << 10));              // 256 KiB
  float* wprime = (float*)(ws + ((size_t)64 << 20) + (320u << 10));
  float* bterm  = (float*)(ws + ((size_t)64 << 20) + (328u << 10));
  float* zp     = (float*)(ws + ((size_t)64 << 20) + (336u << 10));             // 512 KiB
  unsigned short* gb = xb;             // alias: xb dead after k_attn

  float* probs = (float*)d_out;
  float* adj   = probs + 128;

  k_prep<<<6216, 256, 0, stream>>>(x, w1, w2, gin_w, xb, xbT, mt, ginb);
  k_gemm_nt128<<<1024, 256, 0, stream>>>(xb, mt, nullptr, qb);        // q = x (w1 w2^T)
  k_colsum<<<1024, 256, 0, stream>>>(qb, xb, psum);
  k_rcol<<<256, 256, 0, stream>>>(psum, rcolp);
  k_attn<<<1024, 256, 0, stream>>>(qb, xb, xbT, rcolp, adj, hb);      // adj + h=(adj+I)x
  k_gemm_nt128<<<1024, 256, 0, stream>>>(hb, ginb, gin_b, gb);        // g = h gin_w^T + b
  k_bnstats<<<1024, 256, 0, stream>>>(gb, lc_w, lc_b, bn1_g, bn1_b, wprime, bterm);
  k_zred<<<512, 128, 0, stream>>>(gb, wprime, zp);
  k_final<<<1, 1024, 0, stream>>>(zp, bterm, conv_w, conv_b, bn2_g, bn2_b, out_w, out_b, probs);
}

// Round 4
// 556.729 us; speedup vs baseline: 1.1022x; 1.1022x over previous
//
#include <hip/hip_runtime.h>

// ---------------------------------------------------------------------------
// PairEdgeLearnGNN on MI355X.  B=64, N=1024, D=128, KT=13, NC=2, CF=2.
//   scores = x (w1 w2^T) x^T ; adj = softmax over axis=1 (columns)
//   h = (adj + I) x ; g = h gin_w^T + gin_b ; BN1 per-n over (b,d)
//   z[b,c,d] = sum_n bn1(g) lc_w[c,n] ; conv K=13 SAME ; BN2 ; relu ; linear ; softmax
// Outputs: probs (64x2) then adj (64x1024x1024), f32, concatenated.
// ---------------------------------------------------------------------------

typedef __attribute__((ext_vector_type(8))) short bf16x8;
typedef __attribute__((ext_vector_type(4))) float f32x4;

__device__ __forceinline__ float b2f(unsigned short s){
  union { unsigned u; float f; } v; v.u = ((unsigned)s) << 16; return v.f;
}
__device__ __forceinline__ unsigned short f2b(float f){
  union { float f; unsigned u; } v; v.f = f;
  unsigned r = v.u + 0x7fffu + ((v.u >> 16) & 1u);
  return (unsigned short)(r >> 16);
}

#define MFMA16(a, b, c) __builtin_amdgcn_mfma_f32_16x16x32_bf16((a), (b), (c), 0, 0, 0)

// ---------------------------------------------------------------------------
// prep (all vectorized):
//  [0,4096)      x -> xb bf16 cast, 16B stores
//  [4096,6144)   64x64 transpose tiles -> xbT, 16B stores
//  [6144,6152)   gin_w -> bf16
//  [6152,6216)   Mt[d][k] = sum_e w1[k,e] w2[d,e]
// ---------------------------------------------------------------------------
__global__ __launch_bounds__(256) void k_prep(
    const float* __restrict__ x, const float* __restrict__ w1, const float* __restrict__ w2,
    const float* __restrict__ gin_w,
    unsigned short* __restrict__ xb, unsigned short* __restrict__ xbT,
    unsigned short* __restrict__ mt, unsigned short* __restrict__ ginb)
{
  int blk = blockIdx.x, tid = threadIdx.x;
  if (blk < 4096) {
    size_t i = ((size_t)blk << 11) + (tid << 3);
    float4 a = *(const float4*)&x[i];
    float4 c = *(const float4*)&x[i + 4];
    bf16x8 r;
    r[0]=(short)f2b(a.x); r[1]=(short)f2b(a.y); r[2]=(short)f2b(a.z); r[3]=(short)f2b(a.w);
    r[4]=(short)f2b(c.x); r[5]=(short)f2b(c.y); r[6]=(short)f2b(c.z); r[7]=(short)f2b(c.w);
    *(bf16x8*)&xb[i] = r;
  } else if (blk < 6144) {
    __shared__ float tile[64][65];
    int t = blk - 4096;
    int b = t >> 5, tt = t & 31;
    int j0 = (tt >> 1) << 6, d0 = (tt & 1) << 6;
    int row = tid >> 2, cq = tid & 3;
#pragma unroll
    for (int q = 0; q < 4; q++) {
      float4 v = *(const float4*)&x[(((size_t)(b << 10) + j0 + row) << 7) + d0 + (cq << 4) + (q << 2)];
      int c = (cq << 4) + (q << 2);
      tile[row][c] = v.x; tile[row][c+1] = v.y; tile[row][c+2] = v.z; tile[row][c+3] = v.w;
    }
    __syncthreads();
    int d = tid >> 2, jq = tid & 3;
#pragma unroll
    for (int q = 0; q < 2; q++) {
      bf16x8 r;
#pragma unroll
      for (int e = 0; e < 8; e++)
        r[e] = (short)f2b(tile[(jq << 4) + (q << 3) + e][d]);
      *(bf16x8*)&xbT[(((size_t)(b << 7) + d0 + d) << 10) + j0 + (jq << 4) + (q << 3)] = r;
    }
  } else if (blk < 6152) {
    int i = ((blk - 6144) << 11) + (tid << 3);
    float4 a = *(const float4*)&gin_w[i];
    float4 c = *(const float4*)&gin_w[i + 4];
    bf16x8 r;
    r[0]=(short)f2b(a.x); r[1]=(short)f2b(a.y); r[2]=(short)f2b(a.z); r[3]=(short)f2b(a.w);
    r[4]=(short)f2b(c.x); r[5]=(short)f2b(c.y); r[6]=(short)f2b(c.z); r[7]=(short)f2b(c.w);
    *(bf16x8*)&ginb[i] = r;
  } else {
    int i = ((blk - 6152) << 8) + tid;
    int d = i >> 7, k = i & 127;
    float s = 0.f;
    for (int e = 0; e < 128; ++e) s += w1[(k << 7) + e] * w2[(d << 7) + e];
    mt[(d << 7) + k] = f2b(s);
  }
}

// ---------------------------------------------------------------------------
// NT GEMM, M x 128, K=128, 16 rows/wave, 64 rows/block, coalesced bf16 out
// via padded LDS bounce (row stride 136 u16 = 272B, 16B-aligned).
// ---------------------------------------------------------------------------
__global__ __launch_bounds__(256, 4) void k_gemm_nt128(
    const unsigned short* __restrict__ A, const unsigned short* __restrict__ Bt,
    const float* __restrict__ bias, unsigned short* __restrict__ Out)
{
  __shared__ unsigned short sm[64 * 136];
  int row0 = blockIdx.x << 6;
  int tid = threadIdx.x;
  int wave = tid >> 6, lane = tid & 63, lr = lane & 15, lg = lane >> 4;
  int rw = row0 + (wave << 4);
  bf16x8 af[4];
#pragma unroll
  for (int kk = 0; kk < 4; kk++)
    af[kk] = *(const bf16x8*)&A[((size_t)(rw + lr) << 7) + (kk << 5) + (lg << 3)];
  f32x4 acc[8] = {};
#pragma unroll
  for (int kk = 0; kk < 4; kk++) {
    bf16x8 bb[8];
#pragma unroll
    for (int cf = 0; cf < 8; cf++)
      bb[cf] = *(const bf16x8*)&Bt[(((cf << 4) + lr) << 7) + (kk << 5) + (lg << 3)];
#pragma unroll
    for (int cf = 0; cf < 8; cf++)
      acc[cf] = MFMA16(af[kk], bb[cf], acc[cf]);
  }
#pragma unroll
  for (int cf = 0; cf < 8; cf++) {
    int col = (cf << 4) + lr;
    float bv = bias ? bias[col] : 0.f;
    int srow = (wave << 4) + (lg << 2);
#pragma unroll
    for (int r = 0; r < 4; r++)
      sm[(srow + r) * 136 + col] = f2b(acc[cf][r] + bv);
  }
  __syncthreads();
#pragma unroll
  for (int p = 0; p < 4; p++) {
    int rowl = (p << 4) + (tid >> 4);
    int c0 = (tid & 15) << 3;
    bf16x8 v = *(const bf16x8*)&sm[rowl * 136 + c0];
    *(bf16x8*)&Out[((size_t)(row0 + rowl) << 7) + c0] = v;
  }
}

// ---------------------------------------------------------------------------
// colsum: block = (b, it) 128 rows, 8 waves x 16 rows, barrier-free.
// Deterministic per-wave partials psum[it*8+wave][b*1024+j]. XCD-swizzled.
// ---------------------------------------------------------------------------
__global__ __launch_bounds__(512, 4) void k_colsum(
    const unsigned short* __restrict__ qb, const unsigned short* __restrict__ xb,
    float* __restrict__ psum)
{
  int bid = blockIdx.x;
  int l = ((bid & 7) << 6) + (bid >> 3);      // XCD r gets b in [r*8, r*8+8)
  int b = l >> 3, it = l & 7;
  int tid = threadIdx.x, wave = tid >> 6, lane = tid & 63, lr = lane & 15, lg = lane >> 4;
  const unsigned short* Ab = qb + ((size_t)b << 17);
  const unsigned short* Bb = xb + ((size_t)b << 17);
  int rwave = (it << 7) + (wave << 4);
  bf16x8 af[4];
#pragma unroll
  for (int kk = 0; kk < 4; kk++)
    af[kk] = *(const bf16x8*)&Ab[((size_t)(rwave + lr) << 7) + (kk << 5) + (lg << 3)];

  for (int jt = 0; jt < 8; jt++) {
    int j0 = jt << 7;
    f32x4 s[8] = {};
#pragma unroll
    for (int kk = 0; kk < 4; kk++) {
      bf16x8 bb[8];
#pragma unroll
      for (int cf = 0; cf < 8; cf++)
        bb[cf] = *(const bf16x8*)&Bb[((size_t)(j0 + (cf << 4) + lr) << 7) + (kk << 5) + (lg << 3)];
#pragma unroll
      for (int cf = 0; cf < 8; cf++)
        s[cf] = MFMA16(af[kk], bb[cf], s[cf]);
    }
#pragma unroll
    for (int cf = 0; cf < 8; cf++) {
      float p = 0.f;
#pragma unroll
      for (int r = 0; r < 4; r++) p += __expf(s[cf][r]);
      p += __shfl_xor(p, 16);
      p += __shfl_xor(p, 32);
      if (lane < 16)
        psum[(size_t)((it << 3) + wave) * 65536 + (b << 10) + j0 + (cf << 4) + lane] = p;
    }
  }
}

__global__ void k_rcol(const float* __restrict__ psum, float* __restrict__ rcol)
{
  int i = (blockIdx.x << 8) + threadIdx.x;
  float s = 0.f;
#pragma unroll
  for (int p = 0; p < 64; p++) s += psum[(size_t)p * 65536 + i];
  rcol[i] = 1.f / s;
}

// ---------------------------------------------------------------------------
// fused adj + h = (adj+I)x.  Block = (b, it) 128 rows, 8 waves x 16 rows,
// barrier-free jt loop. Per-wave padded LDS P-tile [16][136] serves the PV
// transpose AND full-line adj stores: one dwordx4/lane, 32 lanes = one
// contiguous 512B row, 2 rows per instruction (every 64B line fully covered).
// ---------------------------------------------------------------------------
__global__ __launch_bounds__(512, 4) void k_attn(
    const unsigned short* __restrict__ qb, const unsigned short* __restrict__ xb,
    const unsigned short* __restrict__ xbT, const float* __restrict__ rcol,
    float* __restrict__ adj, unsigned short* __restrict__ hb)
{
  int bid = blockIdx.x;
  int l = ((bid & 7) << 6) + (bid >> 3);      // XCD r gets b in [r*8, r*8+8)
  int b = l >> 3, it = l & 7;
  int tid = threadIdx.x, wave = tid >> 6, lane = tid & 63, lr = lane & 15, lg = lane >> 4;
  __shared__ unsigned short plds[8][16][136];   // per-wave private, padded
  __shared__ float rc[1024];
  const unsigned short* Ab = qb + ((size_t)b << 17);
  const unsigned short* Xb = xb + ((size_t)b << 17);
  const unsigned short* Xt = xbT + ((size_t)b << 17);

  rc[tid] = rcol[(b << 10) + tid];
  rc[tid + 512] = rcol[(b << 10) + tid + 512];

  int rwave = (it << 7) + (wave << 4);
  bf16x8 af[4];
#pragma unroll
  for (int kk = 0; kk < 4; kk++)
    af[kk] = *(const bf16x8*)&Ab[((size_t)(rwave + lr) << 7) + (kk << 5) + (lg << 3)];

  __syncthreads();   // rc ready; no further block barriers

  f32x4 h[8] = {};
  for (int jt = 0; jt < 8; jt++) {
    int j0 = jt << 7;
    f32x4 s[8] = {};
#pragma unroll
    for (int kk = 0; kk < 4; kk++) {
      bf16x8 bb[8];
#pragma unroll
      for (int cf = 0; cf < 8; cf++)
        bb[cf] = *(const bf16x8*)&Xb[((size_t)(j0 + (cf << 4) + lr) << 7) + (kk << 5) + (lg << 3)];
#pragma unroll
      for (int cf = 0; cf < 8; cf++)
        s[cf] = MFMA16(af[kk], bb[cf], s[cf]);
    }

    // exp * rcol -> per-wave LDS (bf16), padded rows (no swizzle needed)
#pragma unroll
    for (int cf = 0; cf < 8; cf++) {
      int colj = (cf << 4) + lr;
      float rv = rc[j0 + colj];
#pragma unroll
      for (int r = 0; r < 4; r++)
        plds[wave][(lg << 2) + r][colj] = f2b(__expf(s[cf][r]) * rv);
    }
    // no barrier: plds slice is wave-private (lgkmcnt orders intra-wave)

    // PV: h += P @ x   (A-frags from LDS rows, B from xbT)
#pragma unroll
    for (int kk = 0; kk < 4; kk++) {
      bf16x8 pa = *(const bf16x8*)&plds[wave][lr][(kk << 5) + (lg << 3)];
#pragma unroll
      for (int cf = 0; cf < 8; cf++) {
        bf16x8 vb = *(const bf16x8*)&Xt[(((size_t)((cf << 4) + lr)) << 10) + j0 + (kk << 5) + (lg << 3)];
        h[cf] = MFMA16(pa, vb, h[cf]);
      }
    }

    // adj store: rows 2q,2q+1; 32 lanes x 16B = contiguous 512B per row
#pragma unroll
    for (int q = 0; q < 8; q++) {
      int row = (q << 1) + (lane >> 5);
      int c4 = (lane & 31) << 2;             // float col within 128
      const unsigned short* src = &plds[wave][row][c4];
      f32x4 v4;
      v4[0] = b2f(src[0]); v4[1] = b2f(src[1]); v4[2] = b2f(src[2]); v4[3] = b2f(src[3]);
      __builtin_nontemporal_store(v4,
          (f32x4*)&adj[((size_t)((b << 10) + rwave + row) << 10) + j0 + c4]);
    }
  }

  // epilogue: bounce h through plds, add x, coalesced bf16 store
#pragma unroll
  for (int cf = 0; cf < 8; cf++) {
    int colj = (cf << 4) + lr;
#pragma unroll
    for (int r = 0; r < 4; r++)
      plds[wave][(lg << 2) + r][colj] = f2b(h[cf][r]);
  }
#pragma unroll
  for (int q = 0; q < 4; q++) {
    int row = (q << 2) + (lane >> 4);
    int c0 = (lane & 15) << 3;
    bf16x8 v = *(const bf16x8*)&plds[wave][row][c0];
    bf16x8 xv = *(const bf16x8*)&Xb[((size_t)(rwave + row) << 7) + c0];
    bf16x8 o;
#pragma unroll
    for (int e = 0; e < 8; e++)
      o[e] = (short)f2b(b2f((unsigned short)v[e]) + b2f((unsigned short)xv[e]));
    *(bf16x8*)&hb[((size_t)((b << 10) + rwave + row) << 7) + c0] = o;
  }
}

// ---------------------------------------------------------------------------
// BN1 stats per n over (b,d) -> folded lc weights
// ---------------------------------------------------------------------------
__global__ __launch_bounds__(256) void k_bnstats(
    const unsigned short* __restrict__ gb, const float* __restrict__ lc_w,
    const float* __restrict__ lc_b, const float* __restrict__ bn1_g,
    const float* __restrict__ bn1_b, float* __restrict__ wprime, float* __restrict__ bterm)
{
  int n = blockIdx.x, tid = threadIdx.x;
  float s = 0.f, s2 = 0.f;
  for (int i = tid; i < 8192; i += 256) {
    int b = i >> 7, d = i & 127;
    float v = b2f(gb[((size_t)((b << 10) + n) << 7) + d]);
    s += v; s2 += v * v;
  }
  __shared__ float rs[256], rs2[256];
  rs[tid] = s; rs2[tid] = s2;
  __syncthreads();
  for (int o = 128; o > 0; o >>= 1) {
    if (tid < o) { rs[tid] += rs[tid + o]; rs2[tid] += rs2[tid + o]; }
    __syncthreads();
  }
  if (tid == 0) {
    float m = rs[0] * (1.f / 8192.f);
    float var = rs2[0] * (1.f / 8192.f) - m * m;
    float r = rsqrtf(var + 1e-5f);
    float rg = r * bn1_g[n];
    float t = bn1_b[n] - m * rg;
#pragma unroll
    for (int c = 0; c < 2; c++) {
      float w = lc_w[(c << 10) + n];
      wprime[(c << 10) + n] = w * rg;
      float bt = w * t;
      if (n == 0) bt += lc_b[c];
      bterm[(c << 10) + n] = bt;
    }
  }
}

__global__ __launch_bounds__(128) void k_zred(
    const unsigned short* __restrict__ gb, const float* __restrict__ wprime,
    float* __restrict__ zp)
{
  int blk = blockIdx.x;
  int b = blk >> 3, nc = blk & 7, n0 = nc << 7, d = threadIdx.x;
  float a0 = 0.f, a1 = 0.f;
  for (int n = n0; n < n0 + 128; ++n) {
    float w0 = wprime[n], w1v = wprime[1024 + n];
    float g = b2f(gb[((size_t)((b << 10) + n) << 7) + d]);
    a0 += g * w0; a1 += g * w1v;
  }
  zp[(size_t)nc * 16384 + ((b << 1) << 7) + d] = a0;
  zp[(size_t)nc * 16384 + (((b << 1) | 1) << 7) + d] = a1;
}

__global__ __launch_bounds__(1024) void k_final(
    const float* __restrict__ zp, const float* __restrict__ bterm,
    const float* __restrict__ conv_w, const float* __restrict__ conv_b,
    const float* __restrict__ bn2_g, const float* __restrict__ bn2_b,
    const float* __restrict__ out_w, const float* __restrict__ out_b,
    float* __restrict__ probs)
{
  __shared__ float smem[16384];
  __shared__ float bp[2], ms[2];
  __shared__ float cw[26];
  int tid = threadIdx.x;
  if (tid < 26) cw[tid] = conv_w[tid];

  for (int c = 0; c < 2; c++) {
    smem[tid] = bterm[(c << 10) + tid];
    __syncthreads();
    for (int o = 512; o > 0; o >>= 1) {
      if (tid < o) smem[tid] += smem[tid + o];
      __syncthreads();
    }
    if (tid == 0) bp[c] = smem[0];
    __syncthreads();
  }

  for (int i = tid; i < 16384; i += 1024) {
    float s = 0.f;
#pragma unroll
    for (int p = 0; p < 8; p++) s += zp[(size_t)p * 16384 + i];
    smem[i] = s + bp[(i >> 7) & 1];
  }
  __syncthreads();

  float o[8];
  float s = 0.f, s2 = 0.f;
#pragma unroll
  for (int k = 0; k < 8; k++) {
    int i = tid + (k << 10);
    int b = i >> 7, d = i & 127;
    float acc = conv_b[0];
#pragma unroll
    for (int c = 0; c < 2; c++) {
      const float* zrow = &smem[((b << 1) | c) << 7];
#pragma unroll
      for (int t = 0; t < 13; t++) {
        int dd = d + t - 6;
        if (dd >= 0 && dd < 128) acc += zrow[dd] * cw[c * 13 + t];
      }
    }
    o[k] = acc; s += acc; s2 += acc * acc;
  }
  __syncthreads();
  smem[tid] = s; smem[1024 + tid] = s2;
  __syncthreads();
  for (int off = 512; off > 0; off >>= 1) {
    if (tid < off) { smem[tid] += smem[tid + off]; smem[1024 + tid] += smem[1024 + tid + off]; }
    __syncthreads();
  }
  if (tid == 0) {
    float m = smem[0] * (1.f / 8192.f);
    float var = smem[1024] * (1.f / 8192.f) - m * m;
    ms[0] = m; ms[1] = rsqrtf(var + 1e-5f);
  }
  __syncthreads();
  float m = ms[0], r = ms[1], g2 = bn2_g[0], b2v = bn2_b[0];
#pragma unroll
  for (int k = 0; k < 8; k++) {
    int i = tid + (k << 10);
    smem[i & 8191] = fmaxf(0.f, (o[k] - m) * r * g2 + b2v);
  }
  __syncthreads();

  int b = tid >> 4, q = tid & 15;
  float l0 = 0.f, l1 = 0.f;
#pragma unroll
  for (int k = 0; k < 8; k++) {
    int d = q + (k << 4);
    float uv = smem[(b << 7) + d];
    l0 += uv * out_w[d];
    l1 += uv * out_w[128 + d];
  }
#pragma unroll
  for (int off = 8; off > 0; off >>= 1) { l0 += __shfl_xor(l0, off); l1 += __shfl_xor(l1, off); }
  if (q == 0) {
    l0 += out_b[0]; l1 += out_b[1];
    float mm = fmaxf(l0, l1);
    float e0 = __expf(l0 - mm), e1 = __expf(l1 - mm);
    float inv = 1.f / (e0 + e1);
    probs[(b << 1)] = e0 * inv;
    probs[(b << 1) | 1] = e1 * inv;
  }
}

// ---------------------------------------------------------------------------
extern "C" void kernel_launch(void* const* d_in, const int* in_sizes, int n_in,
                              void* d_out, int out_size, void* d_ws, size_t ws_size,
                              hipStream_t stream)
{
  const float* x      = (const float*)d_in[0];
  const float* w1     = (const float*)d_in[1];
  const float* w2     = (const float*)d_in[2];
  const float* gin_w  = (const float*)d_in[3];
  const float* gin_b  = (const float*)d_in[4];
  const float* bn1_g  = (const float*)d_in[5];
  const float* bn1_b  = (const float*)d_in[6];
  const float* lc_w   = (const float*)d_in[7];
  const float* lc_b   = (const float*)d_in[8];
  const float* conv_w = (const float*)d_in[9];
  const float* conv_b = (const float*)d_in[10];
  const float* bn2_g  = (const float*)d_in[11];
  const float* bn2_b  = (const float*)d_in[12];
  const float* out_w  = (const float*)d_in[13];
  const float* out_b  = (const float*)d_in[14];

  char* ws = (char*)d_ws;
  unsigned short* xb   = (unsigned short*)(ws);                       // 16 MiB
  unsigned short* xbT  = (unsigned short*)(ws + ((size_t)16 << 20));  // 16 MiB
  unsigned short* qb   = (unsigned short*)(ws + ((size_t)32 << 20));  // 16 MiB
  unsigned short* hb   = (unsigned short*)(ws + ((size_t)48 << 20));  // 16 MiB
  float* psum = (float*)hb;            // alias: psum dead before hb written
  unsigned short* mt   = (unsigned short*)(ws + ((size_t)64 << 20));            // 32 KiB
  unsigned short* ginb = (unsigned short*)(ws + ((size_t)64 << 20) + (32u << 10));
  float* rcolp  = (float*)(ws + ((size_t)64 << 20) + (64u << 10));              // 256 KiB
  float* wprime = (float*)(ws + ((size_t)64 << 20) + (320u << 10));
  float* bterm  = (float*)(ws + ((size_t)64 << 20) + (328u << 10));
  float* zp     = (float*)(ws + ((size_t)64 << 20) + (336u << 10));             // 512 KiB
  unsigned short* gb = xb;             // alias: xb dead after k_attn

  float* probs = (float*)d_out;
  float* adj   = probs + 128;

  k_prep<<<6216, 256, 0, stream>>>(x, w1, w2, gin_w, xb, xbT, mt, ginb);
  k_gemm_nt128<<<1024, 256, 0, stream>>>(xb, mt, nullptr, qb);        // q = x (w1 w2^T)
  k_colsum<<<512, 512, 0, stream>>>(qb, xb, psum);
  k_rcol<<<256, 256, 0, stream>>>(psum, rcolp);
  k_attn<<<512, 512, 0, stream>>>(qb, xb, xbT, rcolp, adj, hb);       // adj + h=(adj+I)x
  k_gemm_nt128<<<1024, 256, 0, stream>>>(hb, ginb, gin_b, gb);        // g = h gin_w^T + b
  k_bnstats<<<1024, 256, 0, stream>>>(gb, lc_w, lc_b, bn1_g, bn1_b, wprime, bterm);
  k_zred<<<512, 128, 0, stream>>>(gb, wprime, zp);
  k_final<<<1, 1024, 0, stream>>>(zp, bterm, conv_w, conv_b, bn2_g, bn2_b, out_w, out_b, probs);
}

// Round 5
// 538.258 us; speedup vs baseline: 1.1400x; 1.0343x over previous
//
#include <hip/hip_runtime.h>

// ---------------------------------------------------------------------------
// PairEdgeLearnGNN on MI355X.  B=64, N=1024, D=128, KT=13, NC=2, CF=2.
//   scores = x (w1 w2^T) x^T ; adj = softmax over axis=1 (columns)
//   h = (adj + I) x ; g = h gin_w^T + gin_b ; BN1 per-n over (b,d)
//   z[b,c,d] = sum_n bn1(g) lc_w[c,n] ; conv K=13 SAME ; BN2 ; relu ; linear ; softmax
// Outputs: probs (64x2) then adj (64x1024x1024), f32, concatenated.
// ---------------------------------------------------------------------------

typedef __attribute__((ext_vector_type(8))) short bf16x8;
typedef __attribute__((ext_vector_type(4))) float f32x4;

__device__ __forceinline__ float b2f(unsigned short s){
  union { unsigned u; float f; } v; v.u = ((unsigned)s) << 16; return v.f;
}
__device__ __forceinline__ unsigned short f2b(float f){
  union { float f; unsigned u; } v; v.f = f;
  unsigned r = v.u + 0x7fffu + ((v.u >> 16) & 1u);
  return (unsigned short)(r >> 16);
}

#define MFMA16(a, b, c) __builtin_amdgcn_mfma_f32_16x16x32_bf16((a), (b), (c), 0, 0, 0)

// ---------------------------------------------------------------------------
// prep (all vectorized):
//  [0,4096)      x -> xb bf16 cast, 16B stores
//  [4096,6144)   64x64 transpose tiles -> xbT, 16B stores
//  [6144,6152)   gin_w -> bf16
//  [6152,6216)   Mt[d][k] = sum_e w1[k,e] w2[d,e]
// ---------------------------------------------------------------------------
__global__ __launch_bounds__(256) void k_prep(
    const float* __restrict__ x, const float* __restrict__ w1, const float* __restrict__ w2,
    const float* __restrict__ gin_w,
    unsigned short* __restrict__ xb, unsigned short* __restrict__ xbT,
    unsigned short* __restrict__ mt, unsigned short* __restrict__ ginb)
{
  int blk = blockIdx.x, tid = threadIdx.x;
  if (blk < 4096) {
    size_t i = ((size_t)blk << 11) + (tid << 3);
    float4 a = *(const float4*)&x[i];
    float4 c = *(const float4*)&x[i + 4];
    bf16x8 r;
    r[0]=(short)f2b(a.x); r[1]=(short)f2b(a.y); r[2]=(short)f2b(a.z); r[3]=(short)f2b(a.w);
    r[4]=(short)f2b(c.x); r[5]=(short)f2b(c.y); r[6]=(short)f2b(c.z); r[7]=(short)f2b(c.w);
    *(bf16x8*)&xb[i] = r;
  } else if (blk < 6144) {
    __shared__ float tile[64][65];
    int t = blk - 4096;
    int b = t >> 5, tt = t & 31;
    int j0 = (tt >> 1) << 6, d0 = (tt & 1) << 6;
    int row = tid >> 2, cq = tid & 3;
#pragma unroll
    for (int q = 0; q < 4; q++) {
      float4 v = *(const float4*)&x[(((size_t)(b << 10) + j0 + row) << 7) + d0 + (cq << 4) + (q << 2)];
      int c = (cq << 4) + (q << 2);
      tile[row][c] = v.x; tile[row][c+1] = v.y; tile[row][c+2] = v.z; tile[row][c+3] = v.w;
    }
    __syncthreads();
    int d = tid >> 2, jq = tid & 3;
#pragma unroll
    for (int q = 0; q < 2; q++) {
      bf16x8 r;
#pragma unroll
      for (int e = 0; e < 8; e++)
        r[e] = (short)f2b(tile[(jq << 4) + (q << 3) + e][d]);
      *(bf16x8*)&xbT[(((size_t)(b << 7) + d0 + d) << 10) + j0 + (jq << 4) + (q << 3)] = r;
    }
  } else if (blk < 6152) {
    int i = ((blk - 6144) << 11) + (tid << 3);
    float4 a = *(const float4*)&gin_w[i];
    float4 c = *(const float4*)&gin_w[i + 4];
    bf16x8 r;
    r[0]=(short)f2b(a.x); r[1]=(short)f2b(a.y); r[2]=(short)f2b(a.z); r[3]=(short)f2b(a.w);
    r[4]=(short)f2b(c.x); r[5]=(short)f2b(c.y); r[6]=(short)f2b(c.z); r[7]=(short)f2b(c.w);
    *(bf16x8*)&ginb[i] = r;
  } else {
    int i = ((blk - 6152) << 8) + tid;
    int d = i >> 7, k = i & 127;
    float s = 0.f;
    for (int e = 0; e < 128; ++e) s += w1[(k << 7) + e] * w2[(d << 7) + e];
    mt[(d << 7) + k] = f2b(s);
  }
}

// ---------------------------------------------------------------------------
// NT GEMM, M x 128, K=128, 16 rows/wave, 64 rows/block, coalesced bf16 out
// via padded LDS bounce (row stride 136 u16 = 272B, 16B-aligned).
// ---------------------------------------------------------------------------
__global__ __launch_bounds__(256, 2) void k_gemm_nt128(
    const unsigned short* __restrict__ A, const unsigned short* __restrict__ Bt,
    const float* __restrict__ bias, unsigned short* __restrict__ Out)
{
  __shared__ unsigned short sm[64 * 136];
  int row0 = blockIdx.x << 6;
  int tid = threadIdx.x;
  int wave = tid >> 6, lane = tid & 63, lr = lane & 15, lg = lane >> 4;
  int rw = row0 + (wave << 4);
  bf16x8 af[4];
#pragma unroll
  for (int kk = 0; kk < 4; kk++)
    af[kk] = *(const bf16x8*)&A[((size_t)(rw + lr) << 7) + (kk << 5) + (lg << 3)];
  f32x4 acc[8] = {};
#pragma unroll
  for (int kk = 0; kk < 4; kk++) {
    bf16x8 bb[8];
#pragma unroll
    for (int cf = 0; cf < 8; cf++)
      bb[cf] = *(const bf16x8*)&Bt[(((cf << 4) + lr) << 7) + (kk << 5) + (lg << 3)];
#pragma unroll
    for (int cf = 0; cf < 8; cf++)
      acc[cf] = MFMA16(af[kk], bb[cf], acc[cf]);
  }
#pragma unroll
  for (int cf = 0; cf < 8; cf++) {
    int col = (cf << 4) + lr;
    float bv = bias ? bias[col] : 0.f;
    int srow = (wave << 4) + (lg << 2);
#pragma unroll
    for (int r = 0; r < 4; r++)
      sm[(srow + r) * 136 + col] = f2b(acc[cf][r] + bv);
  }
  __syncthreads();
#pragma unroll
  for (int p = 0; p < 4; p++) {
    int rowl = (p << 4) + (tid >> 4);
    int c0 = (tid & 15) << 3;
    bf16x8 v = *(const bf16x8*)&sm[rowl * 136 + c0];
    *(bf16x8*)&Out[((size_t)(row0 + rowl) << 7) + c0] = v;
  }
}

// ---------------------------------------------------------------------------
// colsum: block = (b, it) 128 rows, 8 waves x 16 rows, barrier-free.
// Deterministic per-wave partials psum[it*8+wave][b*1024+j]. XCD-swizzled.
// ---------------------------------------------------------------------------
__global__ __launch_bounds__(512, 2) void k_colsum(
    const unsigned short* __restrict__ qb, const unsigned short* __restrict__ xb,
    float* __restrict__ psum)
{
  int bid = blockIdx.x;
  int l = ((bid & 7) << 6) + (bid >> 3);      // XCD r gets b in [r*8, r*8+8)
  int b = l >> 3, it = l & 7;
  int tid = threadIdx.x, wave = tid >> 6, lane = tid & 63, lr = lane & 15, lg = lane >> 4;
  const unsigned short* Ab = qb + ((size_t)b << 17);
  const unsigned short* Bb = xb + ((size_t)b << 17);
  int rwave = (it << 7) + (wave << 4);
  bf16x8 af[4];
#pragma unroll
  for (int kk = 0; kk < 4; kk++)
    af[kk] = *(const bf16x8*)&Ab[((size_t)(rwave + lr) << 7) + (kk << 5) + (lg << 3)];

  for (int jt = 0; jt < 8; jt++) {
    int j0 = jt << 7;
    f32x4 s[8] = {};
#pragma unroll
    for (int kk = 0; kk < 4; kk++) {
      bf16x8 bb[8];
#pragma unroll
      for (int cf = 0; cf < 8; cf++)
        bb[cf] = *(const bf16x8*)&Bb[((size_t)(j0 + (cf << 4) + lr) << 7) + (kk << 5) + (lg << 3)];
#pragma unroll
      for (int cf = 0; cf < 8; cf++)
        s[cf] = MFMA16(af[kk], bb[cf], s[cf]);
    }
#pragma unroll
    for (int cf = 0; cf < 8; cf++) {
      float p = 0.f;
#pragma unroll
      for (int r = 0; r < 4; r++) p += __expf(s[cf][r]);
      p += __shfl_xor(p, 16);
      p += __shfl_xor(p, 32);
      if (lane < 16)
        psum[(size_t)((it << 3) + wave) * 65536 + (b << 10) + j0 + (cf << 4) + lane] = p;
    }
  }
}

__global__ void k_rcol(const float* __restrict__ psum, float* __restrict__ rcol)
{
  int i = (blockIdx.x << 8) + threadIdx.x;
  float s = 0.f;
#pragma unroll
  for (int p = 0; p < 64; p++) s += psum[(size_t)p * 65536 + i];
  rcol[i] = 1.f / s;
}

// ---------------------------------------------------------------------------
// fused adj + h = (adj+I)x.  Block = (b, it) 128 rows, 8 waves x 16 rows,
// barrier-free jt loop. Per-wave padded LDS P-tile [16][136] serves the PV
// transpose AND full-line adj stores (one dwordx4/lane, 32 lanes = one
// contiguous 512B row, 2 rows per instruction). Plain stores (L2 merges);
// launch_bounds(512,2) so the allocator can batch loads deeply.
// ---------------------------------------------------------------------------
__global__ __launch_bounds__(512, 2) void k_attn(
    const unsigned short* __restrict__ qb, const unsigned short* __restrict__ xb,
    const unsigned short* __restrict__ xbT, const float* __restrict__ rcol,
    float* __restrict__ adj, unsigned short* __restrict__ hb)
{
  int bid = blockIdx.x;
  int l = ((bid & 7) << 6) + (bid >> 3);      // XCD r gets b in [r*8, r*8+8)
  int b = l >> 3, it = l & 7;
  int tid = threadIdx.x, wave = tid >> 6, lane = tid & 63, lr = lane & 15, lg = lane >> 4;
  __shared__ unsigned short plds[8][16][136];   // per-wave private, padded
  __shared__ float rc[1024];
  const unsigned short* Ab = qb + ((size_t)b << 17);
  const unsigned short* Xb = xb + ((size_t)b << 17);
  const unsigned short* Xt = xbT + ((size_t)b << 17);

  rc[tid] = rcol[(b << 10) + tid];
  rc[tid + 512] = rcol[(b << 10) + tid + 512];

  int rwave = (it << 7) + (wave << 4);
  bf16x8 af[4];
#pragma unroll
  for (int kk = 0; kk < 4; kk++)
    af[kk] = *(const bf16x8*)&Ab[((size_t)(rwave + lr) << 7) + (kk << 5) + (lg << 3)];

  __syncthreads();   // rc ready; no further block barriers

  f32x4 h[8] = {};
  for (int jt = 0; jt < 8; jt++) {
    int j0 = jt << 7;
    f32x4 s[8] = {};
#pragma unroll
    for (int kk = 0; kk < 4; kk++) {
      bf16x8 bb[8];
#pragma unroll
      for (int cf = 0; cf < 8; cf++)
        bb[cf] = *(const bf16x8*)&Xb[((size_t)(j0 + (cf << 4) + lr) << 7) + (kk << 5) + (lg << 3)];
#pragma unroll
      for (int cf = 0; cf < 8; cf++)
        s[cf] = MFMA16(af[kk], bb[cf], s[cf]);
    }

    // exp * rcol -> per-wave LDS (bf16), padded rows
#pragma unroll
    for (int cf = 0; cf < 8; cf++) {
      int colj = (cf << 4) + lr;
      float rv = rc[j0 + colj];
#pragma unroll
      for (int r = 0; r < 4; r++)
        plds[wave][(lg << 2) + r][colj] = f2b(__expf(s[cf][r]) * rv);
    }
    // no barrier: plds slice is wave-private (lgkmcnt orders intra-wave)

    // PV: h += P @ x   (A-frags from LDS rows, B from xbT)
#pragma unroll
    for (int kk = 0; kk < 4; kk++) {
      bf16x8 pa = *(const bf16x8*)&plds[wave][lr][(kk << 5) + (lg << 3)];
#pragma unroll
      for (int cf = 0; cf < 8; cf++) {
        bf16x8 vb = *(const bf16x8*)&Xt[(((size_t)((cf << 4) + lr)) << 10) + j0 + (kk << 5) + (lg << 3)];
        h[cf] = MFMA16(pa, vb, h[cf]);
      }
    }

    // adj store: rows 2q,2q+1; 32 lanes x 16B = contiguous 512B per row
#pragma unroll
    for (int q = 0; q < 8; q++) {
      int row = (q << 1) + (lane >> 5);
      int c4 = (lane & 31) << 2;             // float col within 128
      const unsigned short* src = &plds[wave][row][c4];
      f32x4 v4;
      v4[0] = b2f(src[0]); v4[1] = b2f(src[1]); v4[2] = b2f(src[2]); v4[3] = b2f(src[3]);
      *(f32x4*)&adj[((size_t)((b << 10) + rwave + row) << 10) + j0 + c4] = v4;
    }
  }

  // epilogue: bounce h through plds, add x, coalesced bf16 store
#pragma unroll
  for (int cf = 0; cf < 8; cf++) {
    int colj = (cf << 4) + lr;
#pragma unroll
    for (int r = 0; r < 4; r++)
      plds[wave][(lg << 2) + r][colj] = f2b(h[cf][r]);
  }
#pragma unroll
  for (int q = 0; q < 4; q++) {
    int row = (q << 2) + (lane >> 4);
    int c0 = (lane & 15) << 3;
    bf16x8 v = *(const bf16x8*)&plds[wave][row][c0];
    bf16x8 xv = *(const bf16x8*)&Xb[((size_t)(rwave + row) << 7) + c0];
    bf16x8 o;
#pragma unroll
    for (int e = 0; e < 8; e++)
      o[e] = (short)f2b(b2f((unsigned short)v[e]) + b2f((unsigned short)xv[e]));
    *(bf16x8*)&hb[((size_t)((b << 10) + rwave + row) << 7) + c0] = o;
  }
}

// ---------------------------------------------------------------------------
// BN1 stats per n over (b,d) -> folded lc weights
// ---------------------------------------------------------------------------
__global__ __launch_bounds__(256) void k_bnstats(
    const unsigned short* __restrict__ gb, const float* __restrict__ lc_w,
    const float* __restrict__ lc_b, const float* __restrict__ bn1_g,
    const float* __restrict__ bn1_b, float* __restrict__ wprime, float* __restrict__ bterm)
{
  int n = blockIdx.x, tid = threadIdx.x;
  float s = 0.f, s2 = 0.f;
  for (int i = tid; i < 8192; i += 256) {
    int b = i >> 7, d = i & 127;
    float v = b2f(gb[((size_t)((b << 10) + n) << 7) + d]);
    s += v; s2 += v * v;
  }
  __shared__ float rs[256], rs2[256];
  rs[tid] = s; rs2[tid] = s2;
  __syncthreads();
  for (int o = 128; o > 0; o >>= 1) {
    if (tid < o) { rs[tid] += rs[tid + o]; rs2[tid] += rs2[tid + o]; }
    __syncthreads();
  }
  if (tid == 0) {
    float m = rs[0] * (1.f / 8192.f);
    float var = rs2[0] * (1.f / 8192.f) - m * m;
    float r = rsqrtf(var + 1e-5f);
    float rg = r * bn1_g[n];
    float t = bn1_b[n] - m * rg;
#pragma unroll
    for (int c = 0; c < 2; c++) {
      float w = lc_w[(c << 10) + n];
      wprime[(c << 10) + n] = w * rg;
      float bt = w * t;
      if (n == 0) bt += lc_b[c];
      bterm[(c << 10) + n] = bt;
    }
  }
}

__global__ __launch_bounds__(128) void k_zred(
    const unsigned short* __restrict__ gb, const float* __restrict__ wprime,
    float* __restrict__ zp)
{
  int blk = blockIdx.x;
  int b = blk >> 3, nc = blk & 7, n0 = nc << 7, d = threadIdx.x;
  float a0 = 0.f, a1 = 0.f;
  for (int n = n0; n < n0 + 128; ++n) {
    float w0 = wprime[n], w1v = wprime[1024 + n];
    float g = b2f(gb[((size_t)((b << 10) + n) << 7) + d]);
    a0 += g * w0; a1 += g * w1v;
  }
  zp[(size_t)nc * 16384 + ((b << 1) << 7) + d] = a0;
  zp[(size_t)nc * 16384 + (((b << 1) | 1) << 7) + d] = a1;
}

__global__ __launch_bounds__(1024) void k_final(
    const float* __restrict__ zp, const float* __restrict__ bterm,
    const float* __restrict__ conv_w, const float* __restrict__ conv_b,
    const float* __restrict__ bn2_g, const float* __restrict__ bn2_b,
    const float* __restrict__ out_w, const float* __restrict__ out_b,
    float* __restrict__ probs)
{
  __shared__ float smem[16384];
  __shared__ float bp[2], ms[2];
  __shared__ float cw[26];
  int tid = threadIdx.x;
  if (tid < 26) cw[tid] = conv_w[tid];

  for (int c = 0; c < 2; c++) {
    smem[tid] = bterm[(c << 10) + tid];
    __syncthreads();
    for (int o = 512; o > 0; o >>= 1) {
      if (tid < o) smem[tid] += smem[tid + o];
      __syncthreads();
    }
    if (tid == 0) bp[c] = smem[0];
    __syncthreads();
  }

  for (int i = tid; i < 16384; i += 1024) {
    float s = 0.f;
#pragma unroll
    for (int p = 0; p < 8; p++) s += zp[(size_t)p * 16384 + i];
    smem[i] = s + bp[(i >> 7) & 1];
  }
  __syncthreads();

  float o[8];
  float s = 0.f, s2 = 0.f;
#pragma unroll
  for (int k = 0; k < 8; k++) {
    int i = tid + (k << 10);
    int b = i >> 7, d = i & 127;
    float acc = conv_b[0];
#pragma unroll
    for (int c = 0; c < 2; c++) {
      const float* zrow = &smem[((b << 1) | c) << 7];
#pragma unroll
      for (int t = 0; t < 13; t++) {
        int dd = d + t - 6;
        if (dd >= 0 && dd < 128) acc += zrow[dd] * cw[c * 13 + t];
      }
    }
    o[k] = acc; s += acc; s2 += acc * acc;
  }
  __syncthreads();
  smem[tid] = s; smem[1024 + tid] = s2;
  __syncthreads();
  for (int off = 512; off > 0; off >>= 1) {
    if (tid < off) { smem[tid] += smem[tid + off]; smem[1024 + tid] += smem[1024 + tid + off]; }
    __syncthreads();
  }
  if (tid == 0) {
    float m = smem[0] * (1.f / 8192.f);
    float var = smem[1024] * (1.f / 8192.f) - m * m;
    ms[0] = m; ms[1] = rsqrtf(var + 1e-5f);
  }
  __syncthreads();
  float m = ms[0], r = ms[1], g2 = bn2_g[0], b2v = bn2_b[0];
#pragma unroll
  for (int k = 0; k < 8; k++) {
    int i = tid + (k << 10);
    smem[i & 8191] = fmaxf(0.f, (o[k] - m) * r * g2 + b2v);
  }
  __syncthreads();

  int b = tid >> 4, q = tid & 15;
  float l0 = 0.f, l1 = 0.f;
#pragma unroll
  for (int k = 0; k < 8; k++) {
    int d = q + (k << 4);
    float uv = smem[(b << 7) + d];
    l0 += uv * out_w[d];
    l1 += uv * out_w[128 + d];
  }
#pragma unroll
  for (int off = 8; off > 0; off >>= 1) { l0 += __shfl_xor(l0, off); l1 += __shfl_xor(l1, off); }
  if (q == 0) {
    l0 += out_b[0]; l1 += out_b[1];
    float mm = fmaxf(l0, l1);
    float e0 = __expf(l0 - mm), e1 = __expf(l1 - mm);
    float inv = 1.f / (e0 + e1);
    probs[(b << 1)] = e0 * inv;
    probs[(b << 1) | 1] = e1 * inv;
  }
}

// ---------------------------------------------------------------------------
extern "C" void kernel_launch(void* const* d_in, const int* in_sizes, int n_in,
                              void* d_out, int out_size, void* d_ws, size_t ws_size,
                              hipStream_t stream)
{
  const float* x      = (const float*)d_in[0];
  const float* w1     = (const float*)d_in[1];
  const float* w2     = (const float*)d_in[2];
  const float* gin_w  = (const float*)d_in[3];
  const float* gin_b  = (const float*)d_in[4];
  const float* bn1_g  = (const float*)d_in[5];
  const float* bn1_b  = (const float*)d_in[6];
  const float* lc_w   = (const float*)d_in[7];
  const float* lc_b   = (const float*)d_in[8];
  const float* conv_w = (const float*)d_in[9];
  const float* conv_b = (const float*)d_in[10];
  const float* bn2_g  = (const float*)d_in[11];
  const float* bn2_b  = (const float*)d_in[12];
  const float* out_w  = (const float*)d_in[13];
  const float* out_b  = (const float*)d_in[14];

  char* ws = (char*)d_ws;
  unsigned short* xb   = (unsigned short*)(ws);                       // 16 MiB
  unsigned short* xbT  = (unsigned short*)(ws + ((size_t)16 << 20));  // 16 MiB
  unsigned short* qb   = (unsigned short*)(ws + ((size_t)32 << 20));  // 16 MiB
  unsigned short* hb   = (unsigned short*)(ws + ((size_t)48 << 20));  // 16 MiB
  float* psum = (float*)hb;            // alias: psum dead before hb written
  unsigned short* mt   = (unsigned short*)(ws + ((size_t)64 << 20));            // 32 KiB
  unsigned short* ginb = (unsigned short*)(ws + ((size_t)64 << 20) + (32u << 10));
  float* rcolp  = (float*)(ws + ((size_t)64 << 20) + (64u << 10));              // 256 KiB
  float* wprime = (float*)(ws + ((size_t)64 << 20) + (320u << 10));
  float* bterm  = (float*)(ws + ((size_t)64 << 20) + (328u << 10));
  float* zp     = (float*)(ws + ((size_t)64 << 20) + (336u << 10));             // 512 KiB
  unsigned short* gb = xb;             // alias: xb dead after k_attn

  float* probs = (float*)d_out;
  float* adj   = probs + 128;

  k_prep<<<6216, 256, 0, stream>>>(x, w1, w2, gin_w, xb, xbT, mt, ginb);
  k_gemm_nt128<<<1024, 256, 0, stream>>>(xb, mt, nullptr, qb);        // q = x (w1 w2^T)
  k_colsum<<<512, 512, 0, stream>>>(qb, xb, psum);
  k_rcol<<<256, 256, 0, stream>>>(psum, rcolp);
  k_attn<<<512, 512, 0, stream>>>(qb, xb, xbT, rcolp, adj, hb);       // adj + h=(adj+I)x
  k_gemm_nt128<<<1024, 256, 0, stream>>>(hb, ginb, gin_b, gb);        // g = h gin_w^T + b
  k_bnstats<<<1024, 256, 0, stream>>>(gb, lc_w, lc_b, bn1_g, bn1_b, wprime, bterm);
  k_zred<<<512, 128, 0, stream>>>(gb, wprime, zp);
  k_final<<<1, 1024, 0, stream>>>(zp, bterm, conv_w, conv_b, bn2_g, bn2_b, out_w, out_b, probs);
}